// Round 1
// baseline (304.592 us; speedup 1.0000x reference)
//
#include <hip/hip_runtime.h>

// GCN 2-layer: out = A*(relu(A*x*W1 + b1))*W2 + b2  with A = edge scatter-add.
// Reformulated: agg1 = A*x ; h1 = relu(agg1*W1+b1) ; z = h1*W2 ; out = A*z + b2.
// CSR built in-kernel each call (deterministic pipeline; atomic placement order
// only perturbs fp sum order, well within threshold).

__global__ void hist_k(const int* __restrict__ dstv, int* __restrict__ counts, int E) {
  int stride = gridDim.x * blockDim.x;
  for (int i = blockIdx.x * blockDim.x + threadIdx.x; i < E; i += stride)
    atomicAdd(&counts[dstv[i]], 1);
}

__global__ __launch_bounds__(1024) void scan_k(const int* __restrict__ counts,
                                               int* __restrict__ offs, int n) {
  __shared__ int wsum[16], wpre[16];
  __shared__ int running;
  int tid = threadIdx.x, lane = tid & 63, wv = tid >> 6;
  if (tid == 0) { running = 0; offs[0] = 0; }
  __syncthreads();
  for (int base = 0; base < n; base += 4096) {
    int i0 = base + tid * 4;
    int v0 = 0, v1 = 0, v2 = 0, v3 = 0;
    if (i0 + 3 < n) {
      int4 v = *(const int4*)(counts + i0);
      v0 = v.x; v1 = v.y; v2 = v.z; v3 = v.w;
    } else {
      if (i0 < n)     v0 = counts[i0];
      if (i0 + 1 < n) v1 = counts[i0 + 1];
      if (i0 + 2 < n) v2 = counts[i0 + 2];
      if (i0 + 3 < n) v3 = counts[i0 + 3];
    }
    int s = v0 + v1 + v2 + v3;
    int x = s;
    #pragma unroll
    for (int off = 1; off < 64; off <<= 1) {
      int t = __shfl_up(x, off);
      if (lane >= off) x += t;
    }
    if (lane == 63) wsum[wv] = x;
    __syncthreads();
    if (wv == 0 && lane < 16) {
      int ss = wsum[lane];
      #pragma unroll
      for (int off = 1; off < 16; off <<= 1) {
        int t = __shfl_up(ss, off);
        if (lane >= off) ss += t;
      }
      wpre[lane] = ss;
    }
    __syncthreads();
    int excl = x - s + (wv ? wpre[wv - 1] : 0) + running;
    int p = excl + v0;
    if (i0 < n)     offs[i0 + 1] = p;
    p += v1; if (i0 + 1 < n) offs[i0 + 2] = p;
    p += v2; if (i0 + 2 < n) offs[i0 + 3] = p;
    p += v3; if (i0 + 3 < n) offs[i0 + 4] = p;
    __syncthreads();
    if (tid == 0) running += wpre[15];
    __syncthreads();
  }
}

__global__ void scatter_k(const int* __restrict__ srcv, const int* __restrict__ dstv,
                          int* __restrict__ cur, int* __restrict__ adj, int E) {
  int stride = gridDim.x * blockDim.x;
  for (int i = blockIdx.x * blockDim.x + threadIdx.x; i < E; i += stride) {
    int d = dstv[i];
    int p = atomicAdd(&cur[d], 1);   // cur==offs; after this pass offs[d] == end(d)
    adj[p] = srcv[i];
  }
}

// out[node][0:128] = sum over in-edges of feat[src][0:128]. 1 wave per node, float2/lane.
__global__ void agg128_k(const float* __restrict__ feat, const int* __restrict__ adj,
                         const int* __restrict__ ends, float* __restrict__ outp, int n) {
  int lane = threadIdx.x & 63;
  int node = blockIdx.x * 4 + (threadIdx.x >> 6);
  if (node >= n) return;
  int end = ends[node];
  int beg = node ? ends[node - 1] : 0;
  const float2* base = (const float2*)feat;
  float ax = 0.f, ay = 0.f;
  int i = beg;
  for (; i + 4 <= end; i += 4) {
    int s0 = adj[i], s1 = adj[i + 1], s2 = adj[i + 2], s3 = adj[i + 3];
    float2 v0 = base[(size_t)s0 * 64 + lane];
    float2 v1 = base[(size_t)s1 * 64 + lane];
    float2 v2 = base[(size_t)s2 * 64 + lane];
    float2 v3 = base[(size_t)s3 * 64 + lane];
    ax += (v0.x + v1.x) + (v2.x + v3.x);
    ay += (v0.y + v1.y) + (v2.y + v3.y);
  }
  for (; i < end; ++i) {
    float2 v = base[(size_t)adj[i] * 64 + lane];
    ax += v.x; ay += v.y;
  }
  ((float2*)outp)[(size_t)node * 64 + lane] = make_float2(ax, ay);
}

// out[node][0:40] = b2 + sum over in-edges of feat[src][0:40]. 1 wave per node, lanes 0..39.
__global__ void agg40_k(const float* __restrict__ feat, const int* __restrict__ adj,
                        const int* __restrict__ ends, const float* __restrict__ bias,
                        float* __restrict__ outp, int n) {
  int lane = threadIdx.x & 63;
  int node = blockIdx.x * 4 + (threadIdx.x >> 6);
  if (node >= n) return;
  int end = ends[node];
  int beg = node ? ends[node - 1] : 0;
  if (lane < 40) {
    float acc = 0.f;
    int i = beg;
    for (; i + 4 <= end; i += 4) {
      int s0 = adj[i], s1 = adj[i + 1], s2 = adj[i + 2], s3 = adj[i + 3];
      acc += (feat[(size_t)s0 * 40 + lane] + feat[(size_t)s1 * 40 + lane])
           + (feat[(size_t)s2 * 40 + lane] + feat[(size_t)s3 * 40 + lane]);
    }
    for (; i < end; ++i) acc += feat[(size_t)adj[i] * 40 + lane];
    outp[(size_t)node * 40 + lane] = acc + bias[lane];
  }
}

// C[M][256] = relu(A[M][128] @ W[128][256] + bias). BM=64, BN=64, 256 thr, 4x4 micro-tile.
__global__ __launch_bounds__(256) void gemm1_k(const float* __restrict__ A,
                                               const float* __restrict__ W,
                                               const float* __restrict__ bias,
                                               float* __restrict__ C, int M) {
  __shared__ float As[64][132];   // +4 pad: conflict-free scalar a-reads, 16B-aligned rows
  __shared__ float Ws[128][64];
  int row0 = blockIdx.x * 64, col0 = blockIdx.y * 64;
  int tid = threadIdx.x;
  {
    int mm0 = tid >> 5;
    int k4 = (tid & 31) * 4;
    #pragma unroll
    for (int mm = mm0; mm < 64; mm += 8) {
      int r = row0 + mm;
      float4 v = make_float4(0.f, 0.f, 0.f, 0.f);
      if (r < M) v = *(const float4*)(A + (size_t)r * 128 + k4);
      *(float4*)&As[mm][k4] = v;
    }
  }
  {
    int kk0 = tid >> 4;
    int n4 = (tid & 15) * 4;
    #pragma unroll
    for (int kk = kk0; kk < 128; kk += 16)
      *(float4*)&Ws[kk][n4] = *(const float4*)(W + (size_t)kk * 256 + col0 + n4);
  }
  __syncthreads();
  int ty = tid >> 4, tx = tid & 15;
  float acc[4][4] = {};
  #pragma unroll 4
  for (int k = 0; k < 128; ++k) {
    float a0 = As[ty * 4 + 0][k];
    float a1 = As[ty * 4 + 1][k];
    float a2 = As[ty * 4 + 2][k];
    float a3 = As[ty * 4 + 3][k];
    float4 w = *(const float4*)&Ws[k][tx * 4];
    acc[0][0] += a0 * w.x; acc[0][1] += a0 * w.y; acc[0][2] += a0 * w.z; acc[0][3] += a0 * w.w;
    acc[1][0] += a1 * w.x; acc[1][1] += a1 * w.y; acc[1][2] += a1 * w.z; acc[1][3] += a1 * w.w;
    acc[2][0] += a2 * w.x; acc[2][1] += a2 * w.y; acc[2][2] += a2 * w.z; acc[2][3] += a2 * w.w;
    acc[3][0] += a3 * w.x; acc[3][1] += a3 * w.y; acc[3][2] += a3 * w.z; acc[3][3] += a3 * w.w;
  }
  float4 bv = *(const float4*)(bias + col0 + tx * 4);
  #pragma unroll
  for (int i = 0; i < 4; ++i) {
    int r = row0 + ty * 4 + i;
    if (r < M) {
      float4 o;
      o.x = fmaxf(acc[i][0] + bv.x, 0.f);
      o.y = fmaxf(acc[i][1] + bv.y, 0.f);
      o.z = fmaxf(acc[i][2] + bv.z, 0.f);
      o.w = fmaxf(acc[i][3] + bv.w, 0.f);
      *(float4*)(C + (size_t)r * 256 + col0 + tx * 4) = o;
    }
  }
}

// C[M][40] = A[M][256] @ W[256][40]. One thread per output row; W2 staged in LDS (40KB).
__global__ __launch_bounds__(256) void gemm2_k(const float* __restrict__ A,
                                               const float* __restrict__ W,
                                               float* __restrict__ C, int M) {
  __shared__ float Ws[256 * 40];
  int tid = threadIdx.x;
  for (int i = tid; i < 2560; i += 256)
    ((float4*)Ws)[i] = ((const float4*)W)[i];
  __syncthreads();
  int m = blockIdx.x * 256 + tid;
  if (m >= M) return;
  const float4* row = (const float4*)(A + (size_t)m * 256);
  float4 acc[10] = {};
  for (int k4 = 0; k4 < 64; ++k4) {
    float4 a = row[k4];
    #pragma unroll
    for (int j = 0; j < 4; ++j) {
      float av = (j == 0) ? a.x : (j == 1) ? a.y : (j == 2) ? a.z : a.w;
      const float4* wr = (const float4*)(Ws + (k4 * 4 + j) * 40);
      #pragma unroll
      for (int n4 = 0; n4 < 10; ++n4) {
        float4 w = wr[n4];
        acc[n4].x += av * w.x; acc[n4].y += av * w.y;
        acc[n4].z += av * w.z; acc[n4].w += av * w.w;
      }
    }
  }
  float4* o = (float4*)(C + (size_t)m * 40);
  #pragma unroll
  for (int n4 = 0; n4 < 10; ++n4) o[n4] = acc[n4];
}

extern "C" void kernel_launch(void* const* d_in, const int* in_sizes, int n_in,
                              void* d_out, int out_size, void* d_ws, size_t ws_size,
                              hipStream_t stream) {
  const float* x  = (const float*)d_in[0];
  const int*   ei = (const int*)d_in[1];
  const float* W1 = (const float*)d_in[2];
  const float* b1 = (const float*)d_in[3];
  const float* W2 = (const float*)d_in[4];
  const float* b2 = (const float*)d_in[5];
  float* out = (float*)d_out;

  int N = in_sizes[0] / 128;   // 50000
  int E = in_sizes[1] / 2;     // 800000
  const int* src = ei;
  const int* dst = ei + E;

  // workspace carve (~88.5 MB total)
  char* ws = (char*)d_ws;
  size_t off = 0;
  auto carve = [&](size_t bytes) {
    char* p = ws + off;
    off += (bytes + 255) & ~(size_t)255;
    return p;
  };
  float* agg1  = (float*)carve((size_t)N * 128 * 4);
  float* h1    = (float*)carve((size_t)N * 256 * 4);
  float* z     = (float*)carve((size_t)N * 40 * 4);
  int* counts  = (int*)carve((size_t)N * 4);
  int* offs    = (int*)carve((size_t)(N + 1) * 4);
  int* adj     = (int*)carve((size_t)E * 4);

  hipMemsetAsync(counts, 0, (size_t)N * 4, stream);
  hist_k<<<1024, 256, 0, stream>>>(dst, counts, E);
  scan_k<<<1, 1024, 0, stream>>>(counts, offs, N);
  scatter_k<<<1024, 256, 0, stream>>>(src, dst, offs, adj, E);
  agg128_k<<<(N + 3) / 4, 256, 0, stream>>>(x, adj, offs, agg1, N);
  gemm1_k<<<dim3((N + 63) / 64, 4), 256, 0, stream>>>(agg1, W1, b1, h1, N);
  gemm2_k<<<(N + 255) / 256, 256, 0, stream>>>(h1, W2, z, N);
  agg40_k<<<(N + 3) / 4, 256, 0, stream>>>(z, adj, offs, b2, out, N);
}

// Round 2
// 286.742 us; speedup vs baseline: 1.0623x; 1.0623x over previous
//
#include <hip/hip_runtime.h>

// GCN 2-layer: out = A*(relu(A*x*W1 + b1))*W2 + b2  with A = edge scatter-add.
// Reformulated: agg1 = A*x ; h1 = relu(agg1*W1+b1) ; z = h1*W2 ; out = A*z + b2.

__global__ void hist_k(const int* __restrict__ dstv, int* __restrict__ counts, int E) {
  int stride = gridDim.x * blockDim.x;
  for (int i = blockIdx.x * blockDim.x + threadIdx.x; i < E; i += stride)
    atomicAdd(&counts[dstv[i]], 1);
}

#define SCHUNK 4096
// per-chunk inclusive prefix into offs[i+1], chunk total into csum[b]
__global__ __launch_bounds__(1024) void scanA_k(const int* __restrict__ counts,
                                                int* __restrict__ offs,
                                                int* __restrict__ csum, int n) {
  __shared__ int wsum[16], wpre[16];
  int base = blockIdx.x * SCHUNK;
  int tid = threadIdx.x, lane = tid & 63, wv = tid >> 6;
  int i0 = base + tid * 4;
  int v0 = 0, v1 = 0, v2 = 0, v3 = 0;
  if (i0 + 3 < n) {
    int4 v = *(const int4*)(counts + i0);
    v0 = v.x; v1 = v.y; v2 = v.z; v3 = v.w;
  } else {
    if (i0 < n)     v0 = counts[i0];
    if (i0 + 1 < n) v1 = counts[i0 + 1];
    if (i0 + 2 < n) v2 = counts[i0 + 2];
    if (i0 + 3 < n) v3 = counts[i0 + 3];
  }
  int s = v0 + v1 + v2 + v3;
  int x = s;
  #pragma unroll
  for (int off = 1; off < 64; off <<= 1) {
    int t = __shfl_up(x, off);
    if (lane >= off) x += t;
  }
  if (lane == 63) wsum[wv] = x;
  __syncthreads();
  if (wv == 0 && lane < 16) {
    int ss = wsum[lane];
    #pragma unroll
    for (int off = 1; off < 16; off <<= 1) {
      int t = __shfl_up(ss, off);
      if (lane >= off) ss += t;
    }
    wpre[lane] = ss;
  }
  __syncthreads();
  int excl = x - s + (wv ? wpre[wv - 1] : 0);
  int p = excl + v0;
  if (i0 < n)     offs[i0 + 1] = p;
  p += v1; if (i0 + 1 < n) offs[i0 + 2] = p;
  p += v2; if (i0 + 2 < n) offs[i0 + 3] = p;
  p += v3; if (i0 + 3 < n) offs[i0 + 4] = p;
  if (tid == 0) csum[blockIdx.x] = wpre[15];
}

__global__ void scanB_k(int* __restrict__ csum, int nb) {
  int lane = threadIdx.x & 63;
  int v = (lane < nb) ? csum[lane] : 0;
  int x = v;
  #pragma unroll
  for (int off = 1; off < 64; off <<= 1) {
    int t = __shfl_up(x, off);
    if (lane >= off) x += t;
  }
  if (lane < nb) csum[lane] = x - v;   // exclusive base per chunk
}

__global__ __launch_bounds__(1024) void scanC_k(int* __restrict__ offs,
                                                const int* __restrict__ csum, int n) {
  int b = blockIdx.x;
  int add = csum[b];
  if (b == 0 && threadIdx.x == 0) offs[0] = 0;
  if (add == 0) return;
  int i0 = b * SCHUNK + threadIdx.x * 4 + 1;
  #pragma unroll
  for (int j = 0; j < 4; ++j) {
    int i = i0 + j;
    if (i <= n) offs[i] += add;
  }
}

__global__ void scatter_k(const int* __restrict__ srcv, const int* __restrict__ dstv,
                          int* __restrict__ cur, int* __restrict__ adj, int E) {
  int stride = gridDim.x * blockDim.x;
  for (int i = blockIdx.x * blockDim.x + threadIdx.x; i < E; i += stride) {
    int d = dstv[i];
    int p = atomicAdd(&cur[d], 1);   // cur==offs; after this pass offs[d] == end(d)
    adj[p] = srcv[i];
  }
}

// out[node][0:128] = sum over in-edges of feat[src][0:128]. 1 wave per node, float2/lane.
__global__ void agg128_k(const float* __restrict__ feat, const int* __restrict__ adj,
                         const int* __restrict__ ends, float* __restrict__ outp, int n) {
  int lane = threadIdx.x & 63;
  int node = blockIdx.x * 4 + (threadIdx.x >> 6);
  if (node >= n) return;
  int end = ends[node];
  int beg = node ? ends[node - 1] : 0;
  const float2* base = (const float2*)feat;
  float ax = 0.f, ay = 0.f;
  int i = beg;
  for (; i + 4 <= end; i += 4) {
    int s0 = adj[i], s1 = adj[i + 1], s2 = adj[i + 2], s3 = adj[i + 3];
    float2 v0 = base[(size_t)s0 * 64 + lane];
    float2 v1 = base[(size_t)s1 * 64 + lane];
    float2 v2 = base[(size_t)s2 * 64 + lane];
    float2 v3 = base[(size_t)s3 * 64 + lane];
    ax += (v0.x + v1.x) + (v2.x + v3.x);
    ay += (v0.y + v1.y) + (v2.y + v3.y);
  }
  for (; i < end; ++i) {
    float2 v = base[(size_t)adj[i] * 64 + lane];
    ax += v.x; ay += v.y;
  }
  ((float2*)outp)[(size_t)node * 64 + lane] = make_float2(ax, ay);
}

// out[node][0:40] = b2 + sum over in-edges of feat[src][0:40]. 1 wave per node, lanes 0..39.
__global__ void agg40_k(const float* __restrict__ feat, const int* __restrict__ adj,
                        const int* __restrict__ ends, const float* __restrict__ bias,
                        float* __restrict__ outp, int n) {
  int lane = threadIdx.x & 63;
  int node = blockIdx.x * 4 + (threadIdx.x >> 6);
  if (node >= n) return;
  int end = ends[node];
  int beg = node ? ends[node - 1] : 0;
  if (lane < 40) {
    float acc = 0.f;
    int i = beg;
    for (; i + 4 <= end; i += 4) {
      int s0 = adj[i], s1 = adj[i + 1], s2 = adj[i + 2], s3 = adj[i + 3];
      acc += (feat[(size_t)s0 * 40 + lane] + feat[(size_t)s1 * 40 + lane])
           + (feat[(size_t)s2 * 40 + lane] + feat[(size_t)s3 * 40 + lane]);
    }
    for (; i < end; ++i) acc += feat[(size_t)adj[i] * 40 + lane];
    outp[(size_t)node * 40 + lane] = acc + bias[lane];
  }
}

// C[M][256] = relu(A[M][128] @ W[128][256] + bias).
// BM=64, BN=128, BK=32, 256 thr, 4x8 micro-tile, double-buffered LDS.
// A stored transposed in LDS (Ast[k][m]) -> inner loop is 3x ds_read_b128.
__global__ __launch_bounds__(256) void gemm1_k(const float* __restrict__ A,
                                               const float* __restrict__ W,
                                               const float* __restrict__ bias,
                                               float* __restrict__ C, int M) {
  __shared__ float Ast[2][32][68];    // [buf][k][m+pad4]  8.7KB x2
  __shared__ float Ws[2][32][128];    // [buf][k][n]       16KB x2  => 49.4KB total
  const int row0 = blockIdx.x * 64, col0 = blockIdx.y * 128;
  const int tid = threadIdx.x;
  const int amm = tid >> 3, ak4 = (tid & 7) * 4;   // A stage: rows amm,+32 ; k ak4..+3
  const int wn4 = (tid & 31) * 4, wk0 = tid >> 5;  // W stage: k wk0+8i ; col wn4
  float4 ra[2], rw[4];

  // chunk 0
  #pragma unroll
  for (int i = 0; i < 2; ++i) {
    int rr = row0 + amm + i * 32;
    ra[i] = (rr < M) ? *(const float4*)(A + (size_t)rr * 128 + ak4)
                     : make_float4(0.f, 0.f, 0.f, 0.f);
  }
  #pragma unroll
  for (int i = 0; i < 4; ++i)
    rw[i] = *(const float4*)(W + (size_t)(wk0 + i * 8) * 256 + col0 + wn4);
  #pragma unroll
  for (int i = 0; i < 2; ++i) {
    Ast[0][ak4 + 0][amm + i * 32] = ra[i].x;
    Ast[0][ak4 + 1][amm + i * 32] = ra[i].y;
    Ast[0][ak4 + 2][amm + i * 32] = ra[i].z;
    Ast[0][ak4 + 3][amm + i * 32] = ra[i].w;
  }
  #pragma unroll
  for (int i = 0; i < 4; ++i)
    *(float4*)&Ws[0][wk0 + i * 8][wn4] = rw[i];
  __syncthreads();

  const int ty = tid >> 4, tx = tid & 15;
  float acc[4][8] = {};
  #pragma unroll 1
  for (int c = 0; c < 4; ++c) {
    const int cur = c & 1;
    if (c < 3) {   // issue next chunk's global loads; they fly during compute
      int kb = (c + 1) * 32;
      #pragma unroll
      for (int i = 0; i < 2; ++i) {
        int rr = row0 + amm + i * 32;
        ra[i] = (rr < M) ? *(const float4*)(A + (size_t)rr * 128 + kb + ak4)
                         : make_float4(0.f, 0.f, 0.f, 0.f);
      }
      #pragma unroll
      for (int i = 0; i < 4; ++i)
        rw[i] = *(const float4*)(W + (size_t)(kb + wk0 + i * 8) * 256 + col0 + wn4);
    }
    #pragma unroll 4
    for (int k = 0; k < 32; ++k) {
      float4 af = *(const float4*)&Ast[cur][k][ty * 4];
      float4 w0 = *(const float4*)&Ws[cur][k][tx * 8];
      float4 w1 = *(const float4*)&Ws[cur][k][tx * 8 + 4];
      float am[4] = {af.x, af.y, af.z, af.w};
      float wn[8] = {w0.x, w0.y, w0.z, w0.w, w1.x, w1.y, w1.z, w1.w};
      #pragma unroll
      for (int i = 0; i < 4; ++i)
        #pragma unroll
        for (int j = 0; j < 8; ++j)
          acc[i][j] += am[i] * wn[j];
    }
    if (c < 3) {
      __syncthreads();
      const int nxt = cur ^ 1;
      #pragma unroll
      for (int i = 0; i < 2; ++i) {
        Ast[nxt][ak4 + 0][amm + i * 32] = ra[i].x;
        Ast[nxt][ak4 + 1][amm + i * 32] = ra[i].y;
        Ast[nxt][ak4 + 2][amm + i * 32] = ra[i].z;
        Ast[nxt][ak4 + 3][amm + i * 32] = ra[i].w;
      }
      #pragma unroll
      for (int i = 0; i < 4; ++i)
        *(float4*)&Ws[nxt][wk0 + i * 8][wn4] = rw[i];
      __syncthreads();
    }
  }

  float4 bv0 = *(const float4*)(bias + col0 + tx * 8);
  float4 bv1 = *(const float4*)(bias + col0 + tx * 8 + 4);
  #pragma unroll
  for (int i = 0; i < 4; ++i) {
    int r = row0 + ty * 4 + i;
    if (r < M) {
      float4 o0, o1;
      o0.x = fmaxf(acc[i][0] + bv0.x, 0.f);
      o0.y = fmaxf(acc[i][1] + bv0.y, 0.f);
      o0.z = fmaxf(acc[i][2] + bv0.z, 0.f);
      o0.w = fmaxf(acc[i][3] + bv0.w, 0.f);
      o1.x = fmaxf(acc[i][4] + bv1.x, 0.f);
      o1.y = fmaxf(acc[i][5] + bv1.y, 0.f);
      o1.z = fmaxf(acc[i][6] + bv1.z, 0.f);
      o1.w = fmaxf(acc[i][7] + bv1.w, 0.f);
      *(float4*)(C + (size_t)r * 256 + col0 + tx * 8) = o0;
      *(float4*)(C + (size_t)r * 256 + col0 + tx * 8 + 4) = o1;
    }
  }
}

// C[M][40] = A[M][256] @ W[256][40]. One thread per output row; W2 staged in LDS (40KB).
__global__ __launch_bounds__(256) void gemm2_k(const float* __restrict__ A,
                                               const float* __restrict__ W,
                                               float* __restrict__ C, int M) {
  __shared__ float Ws[256 * 40];
  int tid = threadIdx.x;
  for (int i = tid; i < 2560; i += 256)
    ((float4*)Ws)[i] = ((const float4*)W)[i];
  __syncthreads();
  int m = blockIdx.x * 256 + tid;
  if (m >= M) return;
  const float4* row = (const float4*)(A + (size_t)m * 256);
  float4 acc[10] = {};
  for (int k4 = 0; k4 < 64; ++k4) {
    float4 a = row[k4];
    #pragma unroll
    for (int j = 0; j < 4; ++j) {
      float av = (j == 0) ? a.x : (j == 1) ? a.y : (j == 2) ? a.z : a.w;
      const float4* wr = (const float4*)(Ws + (k4 * 4 + j) * 40);
      #pragma unroll
      for (int n4 = 0; n4 < 10; ++n4) {
        float4 w = wr[n4];
        acc[n4].x += av * w.x; acc[n4].y += av * w.y;
        acc[n4].z += av * w.z; acc[n4].w += av * w.w;
      }
    }
  }
  float4* o = (float4*)(C + (size_t)m * 40);
  #pragma unroll
  for (int n4 = 0; n4 < 10; ++n4) o[n4] = acc[n4];
}

extern "C" void kernel_launch(void* const* d_in, const int* in_sizes, int n_in,
                              void* d_out, int out_size, void* d_ws, size_t ws_size,
                              hipStream_t stream) {
  const float* x  = (const float*)d_in[0];
  const int*   ei = (const int*)d_in[1];
  const float* W1 = (const float*)d_in[2];
  const float* b1 = (const float*)d_in[3];
  const float* W2 = (const float*)d_in[4];
  const float* b2 = (const float*)d_in[5];
  float* out = (float*)d_out;

  int N = in_sizes[0] / 128;   // 50000
  int E = in_sizes[1] / 2;     // 800000
  const int* src = ei;
  const int* dst = ei + E;

  char* ws = (char*)d_ws;
  size_t off = 0;
  auto carve = [&](size_t bytes) {
    char* p = ws + off;
    off += (bytes + 255) & ~(size_t)255;
    return p;
  };
  float* agg1  = (float*)carve((size_t)N * 128 * 4);
  float* h1    = (float*)carve((size_t)N * 256 * 4);
  float* z     = (float*)carve((size_t)N * 40 * 4);
  int* counts  = (int*)carve((size_t)N * 4);
  int* offs    = (int*)carve((size_t)(N + 1) * 4);
  int* adj     = (int*)carve((size_t)E * 4);
  int* csum    = (int*)carve(1024 * 4);

  int nb = (N + SCHUNK - 1) / SCHUNK;   // 13

  hipMemsetAsync(counts, 0, (size_t)N * 4, stream);
  hist_k<<<1024, 256, 0, stream>>>(dst, counts, E);
  scanA_k<<<nb, 1024, 0, stream>>>(counts, offs, csum, N);
  scanB_k<<<1, 64, 0, stream>>>(csum, nb);
  scanC_k<<<nb, 1024, 0, stream>>>(offs, csum, N);
  scatter_k<<<1024, 256, 0, stream>>>(src, dst, offs, adj, E);
  agg128_k<<<(N + 3) / 4, 256, 0, stream>>>(x, adj, offs, agg1, N);
  gemm1_k<<<dim3((N + 63) / 64, 2), 256, 0, stream>>>(agg1, W1, b1, h1, N);
  gemm2_k<<<(N + 255) / 256, 256, 0, stream>>>(h1, W2, z, N);
  agg40_k<<<(N + 3) / 4, 256, 0, stream>>>(z, adj, offs, b2, out, N);
}

// Round 3
// 221.035 us; speedup vs baseline: 1.3780x; 1.2973x over previous
//
#include <hip/hip_runtime.h>

typedef unsigned int u32;
typedef unsigned short u16;
using f32x4 = __attribute__((ext_vector_type(4))) float;
using s16x8 = __attribute__((ext_vector_type(8))) short;
using s16x4 = __attribute__((ext_vector_type(4))) short;

__device__ __forceinline__ u16 rne_bf16(float f) {
  u32 u = __float_as_uint(f);
  u += 0x7FFF + ((u >> 16) & 1);
  return (u16)(u >> 16);
}
__device__ __forceinline__ float bf_lo(u32 u) { return __uint_as_float(u << 16); }
__device__ __forceinline__ float bf_hi(u32 u) { return __uint_as_float(u & 0xFFFF0000u); }

// ---------------- CSR build ----------------
__global__ void hist_k(const int* __restrict__ dstv, int* __restrict__ counts, int E) {
  int stride = gridDim.x * blockDim.x;
  for (int i = blockIdx.x * blockDim.x + threadIdx.x; i < E; i += stride)
    atomicAdd(&counts[dstv[i]], 1);
}

#define SCHUNK 4096
__global__ __launch_bounds__(1024) void scanA_k(const int* __restrict__ counts,
                                                int* __restrict__ offs,
                                                int* __restrict__ csum, int n) {
  __shared__ int wsum[16], wpre[16];
  int base = blockIdx.x * SCHUNK;
  int tid = threadIdx.x, lane = tid & 63, wv = tid >> 6;
  int i0 = base + tid * 4;
  int v0 = 0, v1 = 0, v2 = 0, v3 = 0;
  if (i0 + 3 < n) {
    int4 v = *(const int4*)(counts + i0);
    v0 = v.x; v1 = v.y; v2 = v.z; v3 = v.w;
  } else {
    if (i0 < n)     v0 = counts[i0];
    if (i0 + 1 < n) v1 = counts[i0 + 1];
    if (i0 + 2 < n) v2 = counts[i0 + 2];
    if (i0 + 3 < n) v3 = counts[i0 + 3];
  }
  int s = v0 + v1 + v2 + v3;
  int x = s;
  #pragma unroll
  for (int off = 1; off < 64; off <<= 1) {
    int t = __shfl_up(x, off);
    if (lane >= off) x += t;
  }
  if (lane == 63) wsum[wv] = x;
  __syncthreads();
  if (wv == 0 && lane < 16) {
    int ss = wsum[lane];
    #pragma unroll
    for (int off = 1; off < 16; off <<= 1) {
      int t = __shfl_up(ss, off);
      if (lane >= off) ss += t;
    }
    wpre[lane] = ss;
  }
  __syncthreads();
  int excl = x - s + (wv ? wpre[wv - 1] : 0);
  int p = excl + v0;
  if (i0 < n)     offs[i0 + 1] = p;
  p += v1; if (i0 + 1 < n) offs[i0 + 2] = p;
  p += v2; if (i0 + 2 < n) offs[i0 + 3] = p;
  p += v3; if (i0 + 3 < n) offs[i0 + 4] = p;
  if (tid == 0) csum[blockIdx.x] = wpre[15];
}

__global__ void scanB_k(int* __restrict__ csum, int nb) {
  int lane = threadIdx.x & 63;
  int v = (lane < nb) ? csum[lane] : 0;
  int x = v;
  #pragma unroll
  for (int off = 1; off < 64; off <<= 1) {
    int t = __shfl_up(x, off);
    if (lane >= off) x += t;
  }
  if (lane < nb) csum[lane] = x - v;
}

__global__ __launch_bounds__(1024) void scanC_k(int* __restrict__ offs,
                                                const int* __restrict__ csum, int n) {
  int b = blockIdx.x;
  int add = csum[b];
  if (b == 0 && threadIdx.x == 0) offs[0] = 0;
  if (add == 0) return;
  int i0 = b * SCHUNK + threadIdx.x * 4 + 1;
  #pragma unroll
  for (int j = 0; j < 4; ++j) {
    int i = i0 + j;
    if (i <= n) offs[i] += add;
  }
}

__global__ void scatter_k(const int* __restrict__ srcv, const int* __restrict__ dstv,
                          int* __restrict__ cur, int* __restrict__ adj, int E) {
  int stride = gridDim.x * blockDim.x;
  for (int i = blockIdx.x * blockDim.x + threadIdx.x; i < E; i += stride) {
    int d = dstv[i];
    int p = atomicAdd(&cur[d], 1);
    adj[p] = srcv[i];
  }
}

// ---------------- bf16 conversions ----------------
__global__ void cvtx_k(const float2* __restrict__ x, u32* __restrict__ xb, int n2) {
  int i = blockIdx.x * blockDim.x + threadIdx.x;
  if (i >= n2) return;
  float2 v = x[i];
  xb[i] = (u32)rne_bf16(v.x) | ((u32)rne_bf16(v.y) << 16);
}
// W1 [128][256] f32 -> W1t [256][128] bf16
__global__ void cvtw1_k(const float* __restrict__ W, u16* __restrict__ Wt) {
  int idx = blockIdx.x * blockDim.x + threadIdx.x;
  if (idx >= 256 * 128) return;
  int n = idx >> 7, k = idx & 127;
  Wt[idx] = rne_bf16(W[k * 256 + n]);
}
// W2 [256][40] f32 -> W2t [48][256] bf16 (zero-pad cols 40..47)
__global__ void cvtw2_k(const float* __restrict__ W, u16* __restrict__ Wt) {
  int idx = blockIdx.x * blockDim.x + threadIdx.x;
  if (idx >= 48 * 256) return;
  int c = idx >> 8, k = idx & 255;
  Wt[idx] = (c < 40) ? rne_bf16(W[k * 40 + c]) : (u16)0;
}

// ---------------- aggregation ----------------
// agg1b[node][0:128] = sum_{in-edges} xb[src][0:128]; bf16 in, f32 accum, bf16 out.
__global__ void agg128_k(const u32* __restrict__ xb, const int* __restrict__ adj,
                         const int* __restrict__ ends, u32* __restrict__ aggb, int n) {
  int lane = threadIdx.x & 63;
  int node = blockIdx.x * 4 + (threadIdx.x >> 6);
  if (node >= n) return;
  int end = ends[node];
  int beg = node ? ends[node - 1] : 0;
  float ax = 0.f, ay = 0.f;
  int i = beg;
  for (; i + 4 <= end; i += 4) {
    u32 u0 = xb[(size_t)adj[i] * 64 + lane];
    u32 u1 = xb[(size_t)adj[i + 1] * 64 + lane];
    u32 u2 = xb[(size_t)adj[i + 2] * 64 + lane];
    u32 u3 = xb[(size_t)adj[i + 3] * 64 + lane];
    ax += (bf_lo(u0) + bf_lo(u1)) + (bf_lo(u2) + bf_lo(u3));
    ay += (bf_hi(u0) + bf_hi(u1)) + (bf_hi(u2) + bf_hi(u3));
  }
  for (; i < end; ++i) {
    u32 u = xb[(size_t)adj[i] * 64 + lane];
    ax += bf_lo(u); ay += bf_hi(u);
  }
  aggb[(size_t)node * 64 + lane] = (u32)rne_bf16(ax) | ((u32)rne_bf16(ay) << 16);
}

// out[node][0:40] = b2 + sum_{in-edges} z[src][0:40]
__global__ void agg40_k(const float* __restrict__ feat, const int* __restrict__ adj,
                        const int* __restrict__ ends, const float* __restrict__ bias,
                        float* __restrict__ outp, int n) {
  int lane = threadIdx.x & 63;
  int node = blockIdx.x * 4 + (threadIdx.x >> 6);
  if (node >= n) return;
  int end = ends[node];
  int beg = node ? ends[node - 1] : 0;
  if (lane < 40) {
    float acc = 0.f;
    int i = beg;
    for (; i + 4 <= end; i += 4) {
      int s0 = adj[i], s1 = adj[i + 1], s2 = adj[i + 2], s3 = adj[i + 3];
      acc += (feat[(size_t)s0 * 40 + lane] + feat[(size_t)s1 * 40 + lane])
           + (feat[(size_t)s2 * 40 + lane] + feat[(size_t)s3 * 40 + lane]);
    }
    for (; i < end; ++i) acc += feat[(size_t)adj[i] * 40 + lane];
    outp[(size_t)node * 40 + lane] = acc + bias[lane];
  }
}

// ---------------- fused MFMA: z = relu(Ab@W1 + b1) @ W2 ----------------
// One wave per 16 rows. Swapped-operand mfma(W,A) -> D^T: lane owns row m0+(l&15),
// 4 consecutive cols (l>>4)*4+r. h1 (bf16) lives only in a wave-private LDS tile.
__global__ __launch_bounds__(64) void fused_k(const u16* __restrict__ Ab,
                                              const u16* __restrict__ W1t,
                                              const float* __restrict__ b1,
                                              const u16* __restrict__ W2t,
                                              float* __restrict__ z, int M) {
  __shared__ short h1L[16 * 264];   // row stride 264 shorts (528B, pad vs 512)
  const int l = threadIdx.x;
  const int p = l & 15, g = l >> 4;
  const int m0 = blockIdx.x * 16;
  const int mrow = m0 + p;
  const int mload = (mrow < M) ? mrow : (M - 1);

  // A-fragments for K=128 (4 k-tiles): lane holds Ab[mload][kt*32 + g*8 .. +7]
  s16x8 af[4];
  {
    const u16* arow = Ab + (size_t)mload * 128 + g * 8;
    #pragma unroll
    for (int kt = 0; kt < 4; ++kt)
      af[kt] = *(const s16x8*)(arow + kt * 32);
  }

  // Layer 1: 16 N-tiles of 16 cols
  #pragma unroll 2
  for (int n = 0; n < 16; ++n) {
    const u16* wrow = W1t + (size_t)(n * 16 + p) * 128 + g * 8;
    f32x4 acc = {0.f, 0.f, 0.f, 0.f};
    #pragma unroll
    for (int kt = 0; kt < 4; ++kt) {
      s16x8 bf = *(const s16x8*)(wrow + kt * 32);
      acc = __builtin_amdgcn_mfma_f32_16x16x32_bf16(bf, af[kt], acc, 0, 0, 0);
    }
    float4 bv = *(const float4*)(b1 + n * 16 + g * 4);
    s16x4 pk;
    pk[0] = (short)rne_bf16(fmaxf(acc[0] + bv.x, 0.f));
    pk[1] = (short)rne_bf16(fmaxf(acc[1] + bv.y, 0.f));
    pk[2] = (short)rne_bf16(fmaxf(acc[2] + bv.z, 0.f));
    pk[3] = (short)rne_bf16(fmaxf(acc[3] + bv.w, 0.f));
    *(s16x4*)&h1L[p * 264 + n * 16 + g * 4] = pk;   // 8B store, 2-way max
  }

  // Layer 2: K=256 (8 k-tiles), 3 N-tiles (cols 0..47, 40..47 are zero-pad)
  s16x8 a2[8];
  #pragma unroll
  for (int kt = 0; kt < 8; ++kt)
    a2[kt] = *(const s16x8*)&h1L[p * 264 + kt * 32 + g * 8];

  #pragma unroll
  for (int n2 = 0; n2 < 3; ++n2) {
    const u16* wrow = W2t + (size_t)(n2 * 16 + p) * 256 + g * 8;
    f32x4 acc = {0.f, 0.f, 0.f, 0.f};
    #pragma unroll
    for (int kt = 0; kt < 8; ++kt) {
      s16x8 bf = *(const s16x8*)(wrow + kt * 32);
      acc = __builtin_amdgcn_mfma_f32_16x16x32_bf16(bf, a2[kt], acc, 0, 0, 0);
    }
    int c0 = n2 * 16 + g * 4;
    if (mrow < M && c0 < 40) {
      float4 o; o.x = acc[0]; o.y = acc[1]; o.z = acc[2]; o.w = acc[3];
      *(float4*)(z + (size_t)mrow * 40 + c0) = o;
    }
  }
}

extern "C" void kernel_launch(void* const* d_in, const int* in_sizes, int n_in,
                              void* d_out, int out_size, void* d_ws, size_t ws_size,
                              hipStream_t stream) {
  const float* x  = (const float*)d_in[0];
  const int*   ei = (const int*)d_in[1];
  const float* W1 = (const float*)d_in[2];
  const float* b1 = (const float*)d_in[3];
  const float* W2 = (const float*)d_in[4];
  const float* b2 = (const float*)d_in[5];
  float* out = (float*)d_out;

  int N = in_sizes[0] / 128;   // 50000
  int E = in_sizes[1] / 2;     // 800000
  const int* src = ei;
  const int* dst = ei + E;

  char* ws = (char*)d_ws;
  size_t off = 0;
  auto carve = [&](size_t bytes) {
    char* p = ws + off;
    off += (bytes + 255) & ~(size_t)255;
    return p;
  };
  u32* xb    = (u32*)carve((size_t)N * 128 * 2);   // x as bf16
  u32* aggb  = (u32*)carve((size_t)N * 128 * 2);   // agg1 as bf16
  u16* W1t   = (u16*)carve(256 * 128 * 2);
  u16* W2t   = (u16*)carve(48 * 256 * 2);
  float* z   = (float*)carve((size_t)N * 40 * 4);
  int* counts = (int*)carve((size_t)N * 4);
  int* offs   = (int*)carve((size_t)(N + 1) * 4);
  int* adj    = (int*)carve((size_t)E * 4);
  int* csum   = (int*)carve(1024 * 4);

  int nb = (N + SCHUNK - 1) / SCHUNK;

  hipMemsetAsync(counts, 0, (size_t)N * 4, stream);
  cvtx_k<<<(N * 64 + 255) / 256, 256, 0, stream>>>((const float2*)x, xb, N * 64);
  cvtw1_k<<<(256 * 128 + 255) / 256, 256, 0, stream>>>(W1, W1t);
  cvtw2_k<<<(48 * 256 + 255) / 256, 256, 0, stream>>>(W2, W2t);
  hist_k<<<1024, 256, 0, stream>>>(dst, counts, E);
  scanA_k<<<nb, 1024, 0, stream>>>(counts, offs, csum, N);
  scanB_k<<<1, 64, 0, stream>>>(csum, nb);
  scanC_k<<<nb, 1024, 0, stream>>>(offs, csum, N);
  scatter_k<<<1024, 256, 0, stream>>>(src, dst, offs, adj, E);
  agg128_k<<<(N + 3) / 4, 256, 0, stream>>>(xb, adj, offs, aggb, N);
  fused_k<<<(N + 15) / 16, 64, 0, stream>>>((const u16*)aggb, W1t, b1, W2t, z, N);
  agg40_k<<<(N + 3) / 4, 256, 0, stream>>>(z, adj, offs, b2, out, N);
}

// Round 4
// 211.092 us; speedup vs baseline: 1.4429x; 1.0471x over previous
//
#include <hip/hip_runtime.h>

typedef unsigned int u32;
typedef unsigned short u16;
using f32x4 = __attribute__((ext_vector_type(4))) float;
using s16x8 = __attribute__((ext_vector_type(8))) short;
using s16x4 = __attribute__((ext_vector_type(4))) short;

__device__ __forceinline__ u16 rne_bf16(float f) {
  u32 u = __float_as_uint(f);
  u += 0x7FFF + ((u >> 16) & 1);
  return (u16)(u >> 16);
}
__device__ __forceinline__ float bf_lo(u32 u) { return __uint_as_float(u << 16); }
__device__ __forceinline__ float bf_hi(u32 u) { return __uint_as_float(u & 0xFFFF0000u); }

// ---------------- CSR build ----------------
__global__ void hist_k(const int* __restrict__ dstv, int* __restrict__ counts, int E) {
  int stride = gridDim.x * blockDim.x;
  for (int i = blockIdx.x * blockDim.x + threadIdx.x; i < E; i += stride)
    atomicAdd(&counts[dstv[i]], 1);
}

#define SCHUNK 4096
__global__ __launch_bounds__(1024) void scanA_k(const int* __restrict__ counts,
                                                int* __restrict__ offs,
                                                int* __restrict__ csum, int n) {
  __shared__ int wsum[16], wpre[16];
  int base = blockIdx.x * SCHUNK;
  int tid = threadIdx.x, lane = tid & 63, wv = tid >> 6;
  int i0 = base + tid * 4;
  int v0 = 0, v1 = 0, v2 = 0, v3 = 0;
  if (i0 + 3 < n) {
    int4 v = *(const int4*)(counts + i0);
    v0 = v.x; v1 = v.y; v2 = v.z; v3 = v.w;
  } else {
    if (i0 < n)     v0 = counts[i0];
    if (i0 + 1 < n) v1 = counts[i0 + 1];
    if (i0 + 2 < n) v2 = counts[i0 + 2];
    if (i0 + 3 < n) v3 = counts[i0 + 3];
  }
  int s = v0 + v1 + v2 + v3;
  int x = s;
  #pragma unroll
  for (int off = 1; off < 64; off <<= 1) {
    int t = __shfl_up(x, off);
    if (lane >= off) x += t;
  }
  if (lane == 63) wsum[wv] = x;
  __syncthreads();
  if (wv == 0 && lane < 16) {
    int ss = wsum[lane];
    #pragma unroll
    for (int off = 1; off < 16; off <<= 1) {
      int t = __shfl_up(ss, off);
      if (lane >= off) ss += t;
    }
    wpre[lane] = ss;
  }
  __syncthreads();
  int excl = x - s + (wv ? wpre[wv - 1] : 0);
  int p = excl + v0;
  if (i0 < n)     offs[i0 + 1] = p;
  p += v1; if (i0 + 1 < n) offs[i0 + 2] = p;
  p += v2; if (i0 + 2 < n) offs[i0 + 3] = p;
  p += v3; if (i0 + 3 < n) offs[i0 + 4] = p;
  if (tid == 0) csum[blockIdx.x] = wpre[15];
}

__global__ void scanB_k(int* __restrict__ csum, int nb) {
  int lane = threadIdx.x & 63;
  int v = (lane < nb) ? csum[lane] : 0;
  int x = v;
  #pragma unroll
  for (int off = 1; off < 64; off <<= 1) {
    int t = __shfl_up(x, off);
    if (lane >= off) x += t;
  }
  if (lane < nb) csum[lane] = x - v;
}

__global__ __launch_bounds__(1024) void scanC_k(int* __restrict__ offs,
                                                const int* __restrict__ csum, int n) {
  int b = blockIdx.x;
  int add = csum[b];
  if (b == 0 && threadIdx.x == 0) offs[0] = 0;
  if (add == 0) return;
  int i0 = b * SCHUNK + threadIdx.x * 4 + 1;
  #pragma unroll
  for (int j = 0; j < 4; ++j) {
    int i = i0 + j;
    if (i <= n) offs[i] += add;
  }
}

// XCD-partitioned scatter: blocks with (blockIdx&7)==p handle only dst in
// partition p => each XCD's adj/cur writes stay in its own L2; dirty data
// flushes as ~3.2MB sequential writeback at kernel end instead of ~51MB of
// random partial-line HBM writes. Correct for ANY block->XCD mapping.
__global__ __launch_bounds__(256) void scatter_k(const int* __restrict__ srcv,
                                                 const int* __restrict__ dstv,
                                                 int* __restrict__ cur,
                                                 int* __restrict__ adj,
                                                 int E, int nbin) {
  int p = blockIdx.x & 7;
  int lo = p * nbin, hi = lo + nbin;
  int g = blockIdx.x >> 3;
  int ngroups = gridDim.x >> 3;
  int stride = ngroups * blockDim.x;
  for (int i = g * blockDim.x + threadIdx.x; i < E; i += stride) {
    int d = dstv[i];
    if (d >= lo && d < hi) {
      int pos = atomicAdd(&cur[d], 1);
      adj[pos] = srcv[i];
    }
  }
}

// ---------------- bf16 conversions ----------------
__global__ void cvtx_k(const float2* __restrict__ x, u32* __restrict__ xb, int n2) {
  int i = blockIdx.x * blockDim.x + threadIdx.x;
  if (i >= n2) return;
  float2 v = x[i];
  xb[i] = (u32)rne_bf16(v.x) | ((u32)rne_bf16(v.y) << 16);
}
// W1 [128][256] f32 -> W1t [256][128] bf16
__global__ void cvtw1_k(const float* __restrict__ W, u16* __restrict__ Wt) {
  int idx = blockIdx.x * blockDim.x + threadIdx.x;
  if (idx >= 256 * 128) return;
  int n = idx >> 7, k = idx & 127;
  Wt[idx] = rne_bf16(W[k * 256 + n]);
}
// W2 [256][40] f32 -> W2t [48][256] bf16 (zero-pad cols 40..47)
__global__ void cvtw2_k(const float* __restrict__ W, u16* __restrict__ Wt) {
  int idx = blockIdx.x * blockDim.x + threadIdx.x;
  if (idx >= 48 * 256) return;
  int c = idx >> 8, k = idx & 255;
  Wt[idx] = (c < 40) ? rne_bf16(W[k * 40 + c]) : (u16)0;
}

// ---------------- aggregation ----------------
__global__ void agg128_k(const u32* __restrict__ xb, const int* __restrict__ adj,
                         const int* __restrict__ ends, u32* __restrict__ aggb, int n) {
  int lane = threadIdx.x & 63;
  int node = blockIdx.x * 4 + (threadIdx.x >> 6);
  if (node >= n) return;
  int end = ends[node];
  int beg = node ? ends[node - 1] : 0;
  float ax = 0.f, ay = 0.f;
  int i = beg;
  for (; i + 4 <= end; i += 4) {
    u32 u0 = xb[(size_t)adj[i] * 64 + lane];
    u32 u1 = xb[(size_t)adj[i + 1] * 64 + lane];
    u32 u2 = xb[(size_t)adj[i + 2] * 64 + lane];
    u32 u3 = xb[(size_t)adj[i + 3] * 64 + lane];
    ax += (bf_lo(u0) + bf_lo(u1)) + (bf_lo(u2) + bf_lo(u3));
    ay += (bf_hi(u0) + bf_hi(u1)) + (bf_hi(u2) + bf_hi(u3));
  }
  for (; i < end; ++i) {
    u32 u = xb[(size_t)adj[i] * 64 + lane];
    ax += bf_lo(u); ay += bf_hi(u);
  }
  aggb[(size_t)node * 64 + lane] = (u32)rne_bf16(ax) | ((u32)rne_bf16(ay) << 16);
}

__global__ void agg40_k(const float* __restrict__ feat, const int* __restrict__ adj,
                        const int* __restrict__ ends, const float* __restrict__ bias,
                        float* __restrict__ outp, int n) {
  int lane = threadIdx.x & 63;
  int node = blockIdx.x * 4 + (threadIdx.x >> 6);
  if (node >= n) return;
  int end = ends[node];
  int beg = node ? ends[node - 1] : 0;
  if (lane < 40) {
    float acc = 0.f;
    int i = beg;
    for (; i + 4 <= end; i += 4) {
      int s0 = adj[i], s1 = adj[i + 1], s2 = adj[i + 2], s3 = adj[i + 3];
      acc += (feat[(size_t)s0 * 40 + lane] + feat[(size_t)s1 * 40 + lane])
           + (feat[(size_t)s2 * 40 + lane] + feat[(size_t)s3 * 40 + lane]);
    }
    for (; i < end; ++i) acc += feat[(size_t)adj[i] * 40 + lane];
    outp[(size_t)node * 40 + lane] = acc + bias[lane];
  }
}

// ---------------- fused MFMA: z = relu(Ab@W1 + b1) @ W2 ----------------
__global__ __launch_bounds__(64) void fused_k(const u16* __restrict__ Ab,
                                              const u16* __restrict__ W1t,
                                              const float* __restrict__ b1,
                                              const u16* __restrict__ W2t,
                                              float* __restrict__ z, int M) {
  __shared__ short h1L[16 * 264];
  const int l = threadIdx.x;
  const int p = l & 15, g = l >> 4;
  const int m0 = blockIdx.x * 16;
  const int mrow = m0 + p;
  const int mload = (mrow < M) ? mrow : (M - 1);

  s16x8 af[4];
  {
    const u16* arow = Ab + (size_t)mload * 128 + g * 8;
    #pragma unroll
    for (int kt = 0; kt < 4; ++kt)
      af[kt] = *(const s16x8*)(arow + kt * 32);
  }

  #pragma unroll 2
  for (int n = 0; n < 16; ++n) {
    const u16* wrow = W1t + (size_t)(n * 16 + p) * 128 + g * 8;
    f32x4 acc = {0.f, 0.f, 0.f, 0.f};
    #pragma unroll
    for (int kt = 0; kt < 4; ++kt) {
      s16x8 bf = *(const s16x8*)(wrow + kt * 32);
      acc = __builtin_amdgcn_mfma_f32_16x16x32_bf16(bf, af[kt], acc, 0, 0, 0);
    }
    float4 bv = *(const float4*)(b1 + n * 16 + g * 4);
    s16x4 pk;
    pk[0] = (short)rne_bf16(fmaxf(acc[0] + bv.x, 0.f));
    pk[1] = (short)rne_bf16(fmaxf(acc[1] + bv.y, 0.f));
    pk[2] = (short)rne_bf16(fmaxf(acc[2] + bv.z, 0.f));
    pk[3] = (short)rne_bf16(fmaxf(acc[3] + bv.w, 0.f));
    *(s16x4*)&h1L[p * 264 + n * 16 + g * 4] = pk;
  }

  s16x8 a2[8];
  #pragma unroll
  for (int kt = 0; kt < 8; ++kt)
    a2[kt] = *(const s16x8*)&h1L[p * 264 + kt * 32 + g * 8];

  #pragma unroll
  for (int n2 = 0; n2 < 3; ++n2) {
    const u16* wrow = W2t + (size_t)(n2 * 16 + p) * 256 + g * 8;
    f32x4 acc = {0.f, 0.f, 0.f, 0.f};
    #pragma unroll
    for (int kt = 0; kt < 8; ++kt) {
      s16x8 bf = *(const s16x8*)(wrow + kt * 32);
      acc = __builtin_amdgcn_mfma_f32_16x16x32_bf16(bf, a2[kt], acc, 0, 0, 0);
    }
    int c0 = n2 * 16 + g * 4;
    if (mrow < M && c0 < 40) {
      float4 o; o.x = acc[0]; o.y = acc[1]; o.z = acc[2]; o.w = acc[3];
      *(float4*)(z + (size_t)mrow * 40 + c0) = o;
    }
  }
}

extern "C" void kernel_launch(void* const* d_in, const int* in_sizes, int n_in,
                              void* d_out, int out_size, void* d_ws, size_t ws_size,
                              hipStream_t stream) {
  const float* x  = (const float*)d_in[0];
  const int*   ei = (const int*)d_in[1];
  const float* W1 = (const float*)d_in[2];
  const float* b1 = (const float*)d_in[3];
  const float* W2 = (const float*)d_in[4];
  const float* b2 = (const float*)d_in[5];
  float* out = (float*)d_out;

  int N = in_sizes[0] / 128;   // 50000
  int E = in_sizes[1] / 2;     // 800000
  const int* src = ei;
  const int* dst = ei + E;

  char* ws = (char*)d_ws;
  size_t off = 0;
  auto carve = [&](size_t bytes) {
    char* p = ws + off;
    off += (bytes + 255) & ~(size_t)255;
    return p;
  };
  u32* xb    = (u32*)carve((size_t)N * 128 * 2);
  u32* aggb  = (u32*)carve((size_t)N * 128 * 2);
  u16* W1t   = (u16*)carve(256 * 128 * 2);
  u16* W2t   = (u16*)carve(48 * 256 * 2);
  float* z   = (float*)carve((size_t)N * 40 * 4);
  int* counts = (int*)carve((size_t)N * 4);
  int* offs   = (int*)carve((size_t)(N + 1) * 4);
  int* adj    = (int*)carve((size_t)E * 4);
  int* csum   = (int*)carve(1024 * 4);

  int nb = (N + SCHUNK - 1) / SCHUNK;
  int nbin = (N + 7) / 8;   // dst partition width per XCD group

  hipMemsetAsync(counts, 0, (size_t)N * 4, stream);
  cvtx_k<<<(N * 64 + 255) / 256, 256, 0, stream>>>((const float2*)x, xb, N * 64);
  cvtw1_k<<<(256 * 128 + 255) / 256, 256, 0, stream>>>(W1, W1t);
  cvtw2_k<<<(48 * 256 + 255) / 256, 256, 0, stream>>>(W2, W2t);
  hist_k<<<1024, 256, 0, stream>>>(dst, counts, E);
  scanA_k<<<nb, 1024, 0, stream>>>(counts, offs, csum, N);
  scanB_k<<<1, 64, 0, stream>>>(csum, nb);
  scanC_k<<<nb, 1024, 0, stream>>>(offs, csum, N);
  scatter_k<<<1024, 256, 0, stream>>>(src, dst, offs, adj, E, nbin);
  agg128_k<<<(N + 3) / 4, 256, 0, stream>>>(xb, adj, offs, aggb, N);
  fused_k<<<(N + 15) / 16, 64, 0, stream>>>((const u16*)aggb, W1t, b1, W2t, z, N);
  agg40_k<<<(N + 3) / 4, 256, 0, stream>>>(z, adj, offs, b2, out, N);
}